// Round 3
// baseline (379.300 us; speedup 1.0000x reference)
//
#include <hip/hip_runtime.h>
#include <hip/hip_cooperative_groups.h>
#include <math.h>

namespace cg = cooperative_groups;

#define N2   256
#define DIM  768
#define EPSF 1e-8f

// ws layout (float offsets). Everything is written before read on every call
// -> no memset/zeroing needed despite the 0xAA poison.
#define OFF_PART  0u          // [16][2][65536] split-K partial Grams (8 MB)
#define OFF_PDIAG 2097152u    // [16][2][256]   partial diagonals
#define OFF_GS    2105344u    // [65536]
#define OFF_GT    2170880u    // [65536]
#define OFF_INVS  2236416u    // [65536]
#define OFF_INVT  2301952u    // [65536]
#define OFF_SLOT  2367488u    // [1408] per-block result slots
#define SL_DSDT 0     // [512]  blocks 0..255: ds row-sums (s); 256..511: dt (t)
#define SL_CON  512   // [128]
#define SL_ANG  640   // [512]
#define SL_DIST 1152  // [256]

__device__ inline float wave_reduce_sum(float v) {
    #pragma unroll
    for (int o = 32; o > 0; o >>= 1) v += __shfl_down(v, o, 64);
    return v;
}
__device__ inline float wave_reduce_max(float v) {
    #pragma unroll
    for (int o = 32; o > 0; o >>= 1) v = fmaxf(v, __shfl_down(v, o, 64));
    return v;
}
__device__ inline float block_reduce_sum(float v, volatile float* red) {
    float w = wave_reduce_sum(v);
    __syncthreads();
    if ((threadIdx.x & 63) == 0) red[threadIdx.x >> 6] = w;
    __syncthreads();
    return red[0] + red[1] + red[2] + red[3];
}
__device__ inline const float* rowptr(const float* q, const float* p, int r) {
    return (r < 128) ? (q + r * DIM) : (p + (r - 128) * DIM);
}

__global__ __launch_bounds__(256, 2) void fused_kernel(
        const float* __restrict__ sq, const float* __restrict__ sp,
        const float* __restrict__ tq, const float* __restrict__ tp,
        float* __restrict__ ws, float* __restrict__ out) {
    cg::grid_group grid = cg::this_grid();
    __shared__ float pool[6656];          // 26.6 KB, aliased per phase
    __shared__ float red1[4], red2[4], redS[1];
    const int b = blockIdx.x, t = threadIdx.x;

    // =================== P0: Gram GEMM, split-K 16 ===================
    // task: c = K-chunk(48), mat, 64x64 tile. 4x4 per-thread register tile,
    // rows/cols strided by 16 so LDS b128 reads are 2-way (free) not 8-way.
    {
        const int c = b & 15, mat = (b >> 4) & 1, tile = b >> 5;
        const int m0 = (tile >> 2) * 64, n0 = (tile & 3) * 64;
        const float* q = mat ? tq : sq;
        const float* p = mat ? tp : sp;
        float (*As)[52] = (float(*)[52])pool;            // [64][52]
        float (*Bs)[52] = (float(*)[52])(pool + 3328);
        const int srow = t >> 2, skq = (t & 3) * 4;
        const int kb = c * 48;
        const float* arow = rowptr(q, p, m0 + srow);
        const float* brow = rowptr(q, p, n0 + srow);
        #pragma unroll
        for (int m = 0; m < 3; ++m) {
            *(float4*)&As[srow][skq + 16 * m] = *(const float4*)&arow[kb + skq + 16 * m];
            *(float4*)&Bs[srow][skq + 16 * m] = *(const float4*)&brow[kb + skq + 16 * m];
        }
        __syncthreads();
        const int ty = t >> 4, tx = t & 15;
        float acc[4][4] = {};
        for (int k = 0; k < 48; k += 4) {
            float4 av[4], bv[4];
            #pragma unroll
            for (int r = 0; r < 4; ++r) av[r] = *(const float4*)&As[ty + 16 * r][k];
            #pragma unroll
            for (int cc = 0; cc < 4; ++cc) bv[cc] = *(const float4*)&Bs[tx + 16 * cc][k];
            #pragma unroll
            for (int r = 0; r < 4; ++r) {
                const float ar4[4] = {av[r].x, av[r].y, av[r].z, av[r].w};
                #pragma unroll
                for (int cc = 0; cc < 4; ++cc) {
                    const float bc4[4] = {bv[cc].x, bv[cc].y, bv[cc].z, bv[cc].w};
                    acc[r][cc] = fmaf(ar4[0], bc4[0], acc[r][cc]);
                    acc[r][cc] = fmaf(ar4[1], bc4[1], acc[r][cc]);
                    acc[r][cc] = fmaf(ar4[2], bc4[2], acc[r][cc]);
                    acc[r][cc] = fmaf(ar4[3], bc4[3], acc[r][cc]);
                }
            }
        }
        float* P = ws + OFF_PART + (c * 2 + mat) * 65536;
        #pragma unroll
        for (int r = 0; r < 4; ++r) {
            const int row = m0 + ty + 16 * r;
            #pragma unroll
            for (int cc = 0; cc < 4; ++cc)
                P[row * 256 + n0 + tx + 16 * cc] = acc[r][cc];
        }
        if (m0 == n0 && ty == tx) {
            float* PD = ws + OFF_PDIAG + (c * 2 + mat) * 256;
            #pragma unroll
            for (int r = 0; r < 4; ++r) PD[m0 + ty + 16 * r] = acc[r][r];
        }
    }
    __threadfence();
    grid.sync();

    // ====== P1: sum partials -> G, inv, ds row-sums, contrastive ======
    // block b: mat = b>>8, row i = b&255; thread = column j.
    // Diagonals re-summed from PDIAG (coalesced over j; uniform for i).
    {
        const int mat = b >> 8, i = b & 255, j = t;
        const float* P  = ws + OFF_PART + mat * 65536;
        const float* PD = ws + OFF_PDIAG + mat * 256;
        float g = 0.f, dj = 0.f, di = 0.f;
        #pragma unroll
        for (int c = 0; c < 16; ++c) {
            g  += P[c * 131072 + i * 256 + j];
            dj += PD[c * 512 + j];
            di += PD[c * 512 + i];
        }
        float* G  = ws + (mat ? OFF_GT : OFF_GS);
        float* IV = ws + (mat ? OFF_INVT : OFF_INVS);
        G[i * 256 + j] = g;
        const float d = fmaxf(di + dj - 2.f * g, 0.f);
        IV[i * 256 + j] = 1.f / (sqrtf(d) + EPSF);

        const float v = block_reduce_sum((j > i) ? d : 0.f, red1);
        if (t == 0) ws[OFF_SLOT + SL_DSDT + b] = v;

        if (b < 128) {  // contrastive row i (block-uniform branch)
            const float s = (j >= 128) ? 20.f * g : -INFINITY;
            if (j == 128 + i) redS[0] = s;          // diag score
            float m = wave_reduce_max(s);
            __syncthreads();
            if ((t & 63) == 0) red2[t >> 6] = m;
            __syncthreads();
            const float mx = fmaxf(fmaxf(red2[0], red2[1]), fmaxf(red2[2], red2[3]));
            const float e = block_reduce_sum((j >= 128) ? expf(s - mx) : 0.f, red1);
            if (t == 0) ws[OFF_SLOT + SL_CON + b] = mx + logf(e) - redS[0];
        }
    }
    __threadfence();
    grid.sync();

    // =================== P2: angle (all 512) + dist (0..255) ===================
    {
        const float* Gs = ws + OFF_GS;
        const float* Gt = ws + OFF_GT;
        const float* IS = ws + OFF_INVS;
        const float* IT = ws + OFF_INVT;
        float (*sGJ)[68]  = (float(*)[68])pool;
        float (*sIJ)[68]  = (float(*)[68])(pool + 1088);
        float (*sTJ)[68]  = (float(*)[68])(pool + 2176);
        float (*sITJ)[68] = (float(*)[68])(pool + 3264);

        const int k0 = (b & 3) * 64;
        const int j0 = ((b >> 2) & 15) * 16;
        const int i0 = (b >> 6) * 32;
        const int jj = t & 15, ii = t >> 4;
        const int i1 = i0 + ii, i2 = i1 + 16, j = j0 + jj;
        {
            const int r = t >> 4, c = (t & 15) * 4;
            const int g = (j0 + r) * N2 + k0 + c;
            *(float4*)&sGJ[r][c]  = *(const float4*)&Gs[g];
            *(float4*)&sIJ[r][c]  = *(const float4*)&IS[g];
            *(float4*)&sTJ[r][c]  = *(const float4*)&Gt[g];
            *(float4*)&sITJ[r][c] = *(const float4*)&IT[g];
        }
        const float Gjj = Gs[j * 257], Tjj = Gt[j * 257];
        const float wis1 = IS[i1 * N2 + j], wit1 = IT[i1 * N2 + j];
        const float wis2 = IS[i2 * N2 + j], wit2 = IT[i2 * N2 + j];
        const float as1 = (Gjj - Gs[i1 * N2 + j]) * wis1;
        const float at1 = (Tjj - Gt[i1 * N2 + j]) * wit1;
        const float as2 = (Gjj - Gs[i2 * N2 + j]) * wis2;
        const float at2 = (Tjj - Gt[i2 * N2 + j]) * wit2;
        const float* gI1 = Gs + i1 * N2 + k0;
        const float* tI1 = Gt + i1 * N2 + k0;
        const float* gI2 = Gs + i2 * N2 + k0;
        const float* tI2 = Gt + i2 * N2 + k0;
        __syncthreads();

        float sum1 = 0.f, sum2 = 0.f;
        for (int c = 0; c < 64; c += 4) {
            const float4 gJ  = *(const float4*)&sGJ[jj][c];
            const float4 iJ  = *(const float4*)&sIJ[jj][c];
            const float4 tJ  = *(const float4*)&sTJ[jj][c];
            const float4 itJ = *(const float4*)&sITJ[jj][c];
            const float4 a1 = *(const float4*)&gI1[c];
            const float4 b1 = *(const float4*)&tI1[c];
            const float4 a2 = *(const float4*)&gI2[c];
            const float4 b2 = *(const float4*)&tI2[c];
            const float gJr[4]  = {gJ.x, gJ.y, gJ.z, gJ.w};
            const float iJr[4]  = {iJ.x, iJ.y, iJ.z, iJ.w};
            const float tJr[4]  = {tJ.x, tJ.y, tJ.z, tJ.w};
            const float itJr[4] = {itJ.x, itJ.y, itJ.z, itJ.w};
            const float a1r[4] = {a1.x, a1.y, a1.z, a1.w};
            const float b1r[4] = {b1.x, b1.y, b1.z, b1.w};
            const float a2r[4] = {a2.x, a2.y, a2.z, a2.w};
            const float b2r[4] = {b2.x, b2.y, b2.z, b2.w};
            #pragma unroll
            for (int e = 0; e < 4; ++e) {
                const float ps1 = fmaf(wis1, a1r[e] - gJr[e], as1) * iJr[e];
                const float pt1 = fmaf(wit1, b1r[e] - tJr[e], at1) * itJr[e];
                const float d1 = ps1 - pt1;
                const float ad1 = fabsf(d1);
                const float m1 = fminf(ad1, 1.f);
                sum1 = fmaf(m1, fmaf(-0.5f, m1, ad1), sum1);

                const float ps2 = fmaf(wis2, a2r[e] - gJr[e], as2) * iJr[e];
                const float pt2 = fmaf(wit2, b2r[e] - tJr[e], at2) * itJr[e];
                const float d2 = ps2 - pt2;
                const float ad2 = fabsf(d2);
                const float m2 = fminf(ad2, 1.f);
                sum2 = fmaf(m2, fmaf(-0.5f, m2, ad2), sum2);
            }
        }
        const float v = block_reduce_sum(sum1 + sum2, red1);
        if (t == 0) ws[OFF_SLOT + SL_ANG + b] = v;

        if (b < 256) {  // dist row i = b (block-uniform branch)
            __syncthreads();
            const float sds = block_reduce_sum(ws[OFF_SLOT + SL_DSDT + t], red1);
            const float sdt = block_reduce_sum(ws[OFF_SLOT + SL_DSDT + 256 + t], red2);
            const float rs = 1.f / (sds / 32640.f + EPSF);
            const float rt = 1.f / (sdt / 32640.f + EPSF);
            const int i = b;
            const float dsv = fmaxf(Gs[i * 257] + Gs[t * 257] - 2.f * Gs[i * N2 + t], 0.f);
            const float dtv = fmaxf(Gt[i * 257] + Gt[t * 257] - 2.f * Gt[i * N2 + t], 0.f);
            const float dd = dsv * rs - dtv * rt;
            const float a = fabsf(dd);
            const float m = fminf(a, 1.f);
            const float hv = block_reduce_sum((t > i) ? m * fmaf(-0.5f, m, a) : 0.f, red1);
            if (t == 0) ws[OFF_SLOT + SL_DIST + b] = hv;
        }
    }
    __threadfence();
    grid.sync();

    // =================== P3: finalize (block 0) ===================
    if (b == 0) {
        const float* S = ws + OFF_SLOT;
        const float c_ = block_reduce_sum((t < 128) ? S[SL_CON + t] : 0.f, red1);
        const float a_ = block_reduce_sum(S[SL_ANG + t] + S[SL_ANG + 256 + t], red1);
        const float d_ = block_reduce_sum(S[SL_DIST + t], red1);
        if (t == 0) {
            const float contrastive = c_ / 128.f;
            const float dist = d_ / 32640.f;
            const float ang = a_ / 16581120.f;   // 256*255*254
            const float kd = 0.5f * (dist + ang);
            out[0] = contrastive + kd;
            out[1] = contrastive;
            out[2] = kd;
        }
    }
}

extern "C" void kernel_launch(void* const* d_in, const int* in_sizes, int n_in,
                              void* d_out, int out_size, void* d_ws, size_t ws_size,
                              hipStream_t stream) {
    (void)in_sizes; (void)n_in; (void)out_size; (void)ws_size;
    const float* sq = (const float*)d_in[0];
    const float* sp = (const float*)d_in[1];
    const float* tq = (const float*)d_in[2];
    const float* tp = (const float*)d_in[3];
    float* ws  = (float*)d_ws;
    float* out = (float*)d_out;

    void* args[] = {(void*)&sq, (void*)&sp, (void*)&tq, (void*)&tp,
                    (void*)&ws, (void*)&out};
    hipLaunchCooperativeKernel((const void*)fused_kernel, dim3(512), dim3(256),
                               args, 0, stream);
}

// Round 4
// 124.096 us; speedup vs baseline: 3.0565x; 3.0565x over previous
//
#include <hip/hip_runtime.h>
#include <math.h>

#define N2   256
#define DIM  768
#define EPSF 1e-8f

// ws layout (float offsets). Every word is written before read on every call
// -> no zero-init needed despite 0xAA poison. Total ~5.3 MB.
#define OFF_PART  0u          // [8][2][65536] split-K partial Grams (4 MB)
#define OFF_PDIAG 1048576u    // [8][2][256]   partial diagonals
#define OFF_GS    1052672u    // [65536]
#define OFF_GT    1118208u    // [65536]
#define OFF_INVS  1183744u    // [65536]
#define OFF_INVT  1249280u    // [65536]
#define OFF_SLOT  1314816u    // [1408] per-block result slots
#define OFF_CNT   1316224u    // [1] completion counter (zeroed by prep)
#define SL_DSDT 0     // [512]  0..255: ds row-sums (s); 256..511: dt (t)
#define SL_CON  512   // [128]
#define SL_ANG  640   // [512]
#define SL_DIST 1152  // [256]

__device__ inline float wave_reduce_sum(float v) {
    #pragma unroll
    for (int o = 32; o > 0; o >>= 1) v += __shfl_down(v, o, 64);
    return v;
}
__device__ inline float wave_reduce_max(float v) {
    #pragma unroll
    for (int o = 32; o > 0; o >>= 1) v = fmaxf(v, __shfl_down(v, o, 64));
    return v;
}
__device__ inline float block_reduce_sum(float v, volatile float* red) {
    float w = wave_reduce_sum(v);
    __syncthreads();
    if ((threadIdx.x & 63) == 0) red[threadIdx.x >> 6] = w;
    __syncthreads();
    return red[0] + red[1] + red[2] + red[3];
}
__device__ inline const float* rowptr(const float* q, const float* p, int r) {
    return (r < 128) ? (q + r * DIM) : (p + (r - 128) * DIM);
}

// ---------------------------------------------------------------------------
// K1: Gram GEMM, split-K-8. 256 blocks x 256 threads.
// b&7 = K-chunk (96), (b>>3)&1 = matrix, b>>4 = 64x64 tile (4x4 grid).
// 4x4 register tile, rows/cols strided by 16 (LDS b128 reads ~2-way = free).
// Writes partial Gram + partial diagonal; no atomics, no pre-zeroed memory.
// ---------------------------------------------------------------------------
__global__ __launch_bounds__(256) void gemm_kernel(
        const float* __restrict__ sq, const float* __restrict__ sp,
        const float* __restrict__ tq, const float* __restrict__ tp,
        float* __restrict__ ws) {
    const int b = blockIdx.x, t = threadIdx.x;
    const int c = b & 7, mat = (b >> 3) & 1, tile = b >> 4;
    const int m0 = (tile >> 2) * 64, n0 = (tile & 3) * 64;
    const float* q = mat ? tq : sq;
    const float* p = mat ? tp : sp;

    __shared__ float As[64][100];   // 96 k + pad (stride 100: b128 reads 2-way)
    __shared__ float Bs[64][100];

    const int srow = t >> 2, skq = (t & 3) * 4;
    const int kb = c * 96;
    const float* arow = rowptr(q, p, m0 + srow);
    const float* brow = rowptr(q, p, n0 + srow);
    #pragma unroll
    for (int m = 0; m < 6; ++m) {
        *(float4*)&As[srow][skq + 16 * m] = *(const float4*)&arow[kb + skq + 16 * m];
        *(float4*)&Bs[srow][skq + 16 * m] = *(const float4*)&brow[kb + skq + 16 * m];
    }
    __syncthreads();

    const int ty = t >> 4, tx = t & 15;
    float acc[4][4] = {};
    for (int k = 0; k < 96; k += 4) {
        float4 av[4], bv[4];
        #pragma unroll
        for (int r = 0; r < 4; ++r) av[r] = *(const float4*)&As[ty + 16 * r][k];
        #pragma unroll
        for (int cc = 0; cc < 4; ++cc) bv[cc] = *(const float4*)&Bs[tx + 16 * cc][k];
        #pragma unroll
        for (int r = 0; r < 4; ++r) {
            const float ar4[4] = {av[r].x, av[r].y, av[r].z, av[r].w};
            #pragma unroll
            for (int cc = 0; cc < 4; ++cc) {
                const float bc4[4] = {bv[cc].x, bv[cc].y, bv[cc].z, bv[cc].w};
                acc[r][cc] = fmaf(ar4[0], bc4[0], acc[r][cc]);
                acc[r][cc] = fmaf(ar4[1], bc4[1], acc[r][cc]);
                acc[r][cc] = fmaf(ar4[2], bc4[2], acc[r][cc]);
                acc[r][cc] = fmaf(ar4[3], bc4[3], acc[r][cc]);
            }
        }
    }
    float* P = ws + OFF_PART + (unsigned)(c * 2 + mat) * 65536u;
    #pragma unroll
    for (int r = 0; r < 4; ++r) {
        const int row = m0 + ty + 16 * r;
        #pragma unroll
        for (int cc = 0; cc < 4; ++cc)
            P[row * 256 + n0 + tx + 16 * cc] = acc[r][cc];
    }
    if (m0 == n0 && ty == tx) {
        float* PD = ws + OFF_PDIAG + (unsigned)(c * 2 + mat) * 256u;
        #pragma unroll
        for (int r = 0; r < 4; ++r) PD[m0 + ty + 16 * r] = acc[r][r];
    }
}

// ---------------------------------------------------------------------------
// K2: sum partials -> G, inv, ds row-sums (slots), contrastive (slots).
// 512 blocks x 256 threads: mat = b>>8, row i = b&255, thread = column j.
// Also zeroes the K3 completion counter.
// ---------------------------------------------------------------------------
__global__ __launch_bounds__(256) void prep_kernel(float* __restrict__ ws) {
    __shared__ float red1[4], red2[4], redS[1];
    const int b = blockIdx.x, t = threadIdx.x;
    if (b == 0 && t == 0) *(unsigned*)(ws + OFF_CNT) = 0u;

    const int mat = b >> 8, i = b & 255, j = t;
    const float* P  = ws + OFF_PART + (unsigned)mat * 65536u;
    const float* PD = ws + OFF_PDIAG + (unsigned)mat * 256u;
    float g = 0.f, dj = 0.f, di = 0.f;
    #pragma unroll
    for (int c = 0; c < 8; ++c) {
        g  += P[c * 131072 + i * 256 + j];
        dj += PD[c * 512 + j];
        di += PD[c * 512 + i];
    }
    float* G  = ws + (mat ? OFF_GT : OFF_GS);
    float* IV = ws + (mat ? OFF_INVT : OFF_INVS);
    G[i * 256 + j] = g;
    const float d = fmaxf(di + dj - 2.f * g, 0.f);
    IV[i * 256 + j] = 1.f / (sqrtf(d) + EPSF);

    const float v = block_reduce_sum((j > i) ? d : 0.f, red1);
    if (t == 0) ws[OFF_SLOT + SL_DSDT + b] = v;

    if (b < 128) {  // contrastive row i (block-uniform branch)
        const float s = (j >= 128) ? 20.f * g : -INFINITY;
        if (j == 128 + i) redS[0] = s;          // diag score
        float m = wave_reduce_max(s);
        __syncthreads();
        if ((t & 63) == 0) red2[t >> 6] = m;
        __syncthreads();
        const float mx = fmaxf(fmaxf(red2[0], red2[1]), fmaxf(red2[2], red2[3]));
        const float e = block_reduce_sum((j >= 128) ? expf(s - mx) : 0.f, red1);
        if (t == 0) ws[OFF_SLOT + SL_CON + b] = mx + logf(e) - redS[0];
    }
}

// ---------------------------------------------------------------------------
// K3: angle (blocks 0..511) + dist (512..767) + last-block finalize.
// ---------------------------------------------------------------------------
__global__ __launch_bounds__(256) void angle_kernel(float* __restrict__ ws,
                                                    float* __restrict__ out) {
    const float* Gs = ws + OFF_GS;
    const float* Gt = ws + OFF_GT;
    const float* IS = ws + OFF_INVS;
    const float* IT = ws + OFF_INVT;
    __shared__ float sGJ[16][68], sIJ[16][68], sTJ[16][68], sITJ[16][68];
    __shared__ float red1[4], red2[4];
    __shared__ unsigned oldc;
    const int b = blockIdx.x, t = threadIdx.x;

    if (b < 512) {
        const int k0 = (b & 3) * 64;
        const int j0 = ((b >> 2) & 15) * 16;
        const int i0 = (b >> 6) * 32;
        const int jj = t & 15, ii = t >> 4;
        const int i1 = i0 + ii, i2 = i1 + 16, j = j0 + jj;
        {
            const int r = t >> 4, c = (t & 15) * 4;
            const int g = (j0 + r) * N2 + k0 + c;
            *(float4*)&sGJ[r][c]  = *(const float4*)&Gs[g];
            *(float4*)&sIJ[r][c]  = *(const float4*)&IS[g];
            *(float4*)&sTJ[r][c]  = *(const float4*)&Gt[g];
            *(float4*)&sITJ[r][c] = *(const float4*)&IT[g];
        }
        const float Gjj = Gs[j * 257], Tjj = Gt[j * 257];
        const float wis1 = IS[i1 * N2 + j], wit1 = IT[i1 * N2 + j];
        const float wis2 = IS[i2 * N2 + j], wit2 = IT[i2 * N2 + j];
        const float as1 = (Gjj - Gs[i1 * N2 + j]) * wis1;
        const float at1 = (Tjj - Gt[i1 * N2 + j]) * wit1;
        const float as2 = (Gjj - Gs[i2 * N2 + j]) * wis2;
        const float at2 = (Tjj - Gt[i2 * N2 + j]) * wit2;
        const float* gI1 = Gs + i1 * N2 + k0;
        const float* tI1 = Gt + i1 * N2 + k0;
        const float* gI2 = Gs + i2 * N2 + k0;
        const float* tI2 = Gt + i2 * N2 + k0;
        __syncthreads();

        float sum1 = 0.f, sum2 = 0.f;
        for (int c = 0; c < 64; c += 4) {
            const float4 gJ  = *(const float4*)&sGJ[jj][c];
            const float4 iJ  = *(const float4*)&sIJ[jj][c];
            const float4 tJ  = *(const float4*)&sTJ[jj][c];
            const float4 itJ = *(const float4*)&sITJ[jj][c];
            const float4 a1 = *(const float4*)&gI1[c];
            const float4 b1 = *(const float4*)&tI1[c];
            const float4 a2 = *(const float4*)&gI2[c];
            const float4 b2 = *(const float4*)&tI2[c];
            const float gJr[4]  = {gJ.x, gJ.y, gJ.z, gJ.w};
            const float iJr[4]  = {iJ.x, iJ.y, iJ.z, iJ.w};
            const float tJr[4]  = {tJ.x, tJ.y, tJ.z, tJ.w};
            const float itJr[4] = {itJ.x, itJ.y, itJ.z, itJ.w};
            const float a1r[4] = {a1.x, a1.y, a1.z, a1.w};
            const float b1r[4] = {b1.x, b1.y, b1.z, b1.w};
            const float a2r[4] = {a2.x, a2.y, a2.z, a2.w};
            const float b2r[4] = {b2.x, b2.y, b2.z, b2.w};
            #pragma unroll
            for (int e = 0; e < 4; ++e) {
                const float ps1 = fmaf(wis1, a1r[e] - gJr[e], as1) * iJr[e];
                const float pt1 = fmaf(wit1, b1r[e] - tJr[e], at1) * itJr[e];
                const float d1 = ps1 - pt1;
                const float ad1 = fabsf(d1);
                const float m1 = fminf(ad1, 1.f);
                sum1 = fmaf(m1, fmaf(-0.5f, m1, ad1), sum1);

                const float ps2 = fmaf(wis2, a2r[e] - gJr[e], as2) * iJr[e];
                const float pt2 = fmaf(wit2, b2r[e] - tJr[e], at2) * itJr[e];
                const float d2 = ps2 - pt2;
                const float ad2 = fabsf(d2);
                const float m2 = fminf(ad2, 1.f);
                sum2 = fmaf(m2, fmaf(-0.5f, m2, ad2), sum2);
            }
        }
        const float v = block_reduce_sum(sum1 + sum2, red1);
        if (t == 0) ws[OFF_SLOT + SL_ANG + b] = v;
    } else {
        // distance loss, row i = b-512
        const float sds = block_reduce_sum(ws[OFF_SLOT + SL_DSDT + t], red1);
        const float sdt = block_reduce_sum(ws[OFF_SLOT + SL_DSDT + 256 + t], red2);
        const float rs = 1.f / (sds / 32640.f + EPSF);
        const float rt = 1.f / (sdt / 32640.f + EPSF);
        const int i = b - 512;
        const float dsv = fmaxf(Gs[i * 257] + Gs[t * 257] - 2.f * Gs[i * N2 + t], 0.f);
        const float dtv = fmaxf(Gt[i * 257] + Gt[t * 257] - 2.f * Gt[i * N2 + t], 0.f);
        const float dd = dsv * rs - dtv * rt;
        const float a = fabsf(dd);
        const float m = fminf(a, 1.f);
        const float hv = block_reduce_sum((t > i) ? m * fmaf(-0.5f, m, a) : 0.f, red1);
        if (t == 0) ws[OFF_SLOT + SL_DIST + i] = hv;
    }

    // ---- last-block-done finalize ----
    __threadfence();                 // release our slot store to device scope
    if (t == 0) oldc = atomicAdd((unsigned*)(ws + OFF_CNT), 1u);
    __syncthreads();
    if (oldc == 767u) {
        __threadfence();             // acquire
        float* S = ws + OFF_SLOT;
        const float cv = (t < 128)
            ? __hip_atomic_load(&S[SL_CON + t], __ATOMIC_RELAXED, __HIP_MEMORY_SCOPE_AGENT) : 0.f;
        const float av = __hip_atomic_load(&S[SL_ANG + t],       __ATOMIC_RELAXED, __HIP_MEMORY_SCOPE_AGENT)
                       + __hip_atomic_load(&S[SL_ANG + 256 + t], __ATOMIC_RELAXED, __HIP_MEMORY_SCOPE_AGENT);
        const float dv = __hip_atomic_load(&S[SL_DIST + t],      __ATOMIC_RELAXED, __HIP_MEMORY_SCOPE_AGENT);
        const float c_ = block_reduce_sum(cv, red1);
        const float a_ = block_reduce_sum(av, red1);
        const float d_ = block_reduce_sum(dv, red1);
        if (t == 0) {
            const float contrastive = c_ / 128.f;
            const float dist = d_ / 32640.f;
            const float ang = a_ / 16581120.f;   // 256*255*254
            const float kd = 0.5f * (dist + ang);
            out[0] = contrastive + kd;
            out[1] = contrastive;
            out[2] = kd;
        }
    }
}

extern "C" void kernel_launch(void* const* d_in, const int* in_sizes, int n_in,
                              void* d_out, int out_size, void* d_ws, size_t ws_size,
                              hipStream_t stream) {
    (void)in_sizes; (void)n_in; (void)out_size; (void)ws_size;
    const float* sq = (const float*)d_in[0];
    const float* sp = (const float*)d_in[1];
    const float* tq = (const float*)d_in[2];
    const float* tp = (const float*)d_in[3];
    float* ws  = (float*)d_ws;
    float* out = (float*)d_out;

    gemm_kernel<<<256, 256, 0, stream>>>(sq, sp, tq, tp, ws);
    prep_kernel<<<512, 256, 0, stream>>>(ws);
    angle_kernel<<<768, 256, 0, stream>>>(ws, out);
}

// Round 5
// 82.265 us; speedup vs baseline: 4.6107x; 1.5085x over previous
//
#include <hip/hip_runtime.h>
#include <math.h>

#define N2   256
#define DIM  768
#define EPSF 1e-8f

// ws layout (float offsets). Every word is written before read on every call
// -> no zero-init needed despite 0xAA poison. Total ~5.3 MB.
#define OFF_PART  0u          // [8][2][65536] split-K partial Grams (4 MB)
#define OFF_PDIAG 1048576u    // [8][2][256]   partial diagonals
#define OFF_GS    1052672u    // [65536]
#define OFF_GT    1118208u    // [65536]
#define OFF_INVS  1183744u    // [65536]
#define OFF_INVT  1249280u    // [65536]
#define OFF_SLOT  1314816u    // [1408] per-block result slots
#define SL_DSDT 0     // [512]  0..255: ds row-sums (s); 256..511: dt (t)
#define SL_CON  512   // [128]
#define SL_ANG  640   // [512]
#define SL_DIST 1152  // [256]

__device__ inline float wave_reduce_sum(float v) {
    #pragma unroll
    for (int o = 32; o > 0; o >>= 1) v += __shfl_down(v, o, 64);
    return v;
}
__device__ inline float wave_reduce_max(float v) {
    #pragma unroll
    for (int o = 32; o > 0; o >>= 1) v = fmaxf(v, __shfl_down(v, o, 64));
    return v;
}
__device__ inline float block_reduce_sum(float v, volatile float* red) {
    float w = wave_reduce_sum(v);
    __syncthreads();
    if ((threadIdx.x & 63) == 0) red[threadIdx.x >> 6] = w;
    __syncthreads();
    return red[0] + red[1] + red[2] + red[3];
}
__device__ inline const float* rowptr(const float* q, const float* p, int r) {
    return (r < 128) ? (q + r * DIM) : (p + (r - 128) * DIM);
}

// ---------------------------------------------------------------------------
// K1: Gram GEMM, split-K-8. 256 blocks x 256 threads.
// b&7 = K-chunk (96), (b>>3)&1 = matrix, b>>4 = 64x64 tile (4x4 grid).
// 4x4 register tile, rows/cols strided by 16 (LDS b128 reads ~2-way = free).
// Writes partial Gram + partial diagonal; no atomics, no pre-zeroed memory.
// ---------------------------------------------------------------------------
__global__ __launch_bounds__(256) void gemm_kernel(
        const float* __restrict__ sq, const float* __restrict__ sp,
        const float* __restrict__ tq, const float* __restrict__ tp,
        float* __restrict__ ws) {
    const int b = blockIdx.x, t = threadIdx.x;
    const int c = b & 7, mat = (b >> 3) & 1, tile = b >> 4;
    const int m0 = (tile >> 2) * 64, n0 = (tile & 3) * 64;
    const float* q = mat ? tq : sq;
    const float* p = mat ? tp : sp;

    __shared__ float As[64][100];   // 96 k + pad (stride 100: b128 reads 2-way)
    __shared__ float Bs[64][100];

    const int srow = t >> 2, skq = (t & 3) * 4;
    const int kb = c * 96;
    const float* arow = rowptr(q, p, m0 + srow);
    const float* brow = rowptr(q, p, n0 + srow);
    #pragma unroll
    for (int m = 0; m < 6; ++m) {
        *(float4*)&As[srow][skq + 16 * m] = *(const float4*)&arow[kb + skq + 16 * m];
        *(float4*)&Bs[srow][skq + 16 * m] = *(const float4*)&brow[kb + skq + 16 * m];
    }
    __syncthreads();

    const int ty = t >> 4, tx = t & 15;
    float acc[4][4] = {};
    for (int k = 0; k < 96; k += 4) {
        float4 av[4], bv[4];
        #pragma unroll
        for (int r = 0; r < 4; ++r) av[r] = *(const float4*)&As[ty + 16 * r][k];
        #pragma unroll
        for (int cc = 0; cc < 4; ++cc) bv[cc] = *(const float4*)&Bs[tx + 16 * cc][k];
        #pragma unroll
        for (int r = 0; r < 4; ++r) {
            const float ar4[4] = {av[r].x, av[r].y, av[r].z, av[r].w};
            #pragma unroll
            for (int cc = 0; cc < 4; ++cc) {
                const float bc4[4] = {bv[cc].x, bv[cc].y, bv[cc].z, bv[cc].w};
                acc[r][cc] = fmaf(ar4[0], bc4[0], acc[r][cc]);
                acc[r][cc] = fmaf(ar4[1], bc4[1], acc[r][cc]);
                acc[r][cc] = fmaf(ar4[2], bc4[2], acc[r][cc]);
                acc[r][cc] = fmaf(ar4[3], bc4[3], acc[r][cc]);
            }
        }
    }
    float* P = ws + OFF_PART + (unsigned)(c * 2 + mat) * 65536u;
    #pragma unroll
    for (int r = 0; r < 4; ++r) {
        const int row = m0 + ty + 16 * r;
        #pragma unroll
        for (int cc = 0; cc < 4; ++cc)
            P[row * 256 + n0 + tx + 16 * cc] = acc[r][cc];
    }
    if (m0 == n0 && ty == tx) {
        float* PD = ws + OFF_PDIAG + (unsigned)(c * 2 + mat) * 256u;
        #pragma unroll
        for (int r = 0; r < 4; ++r) PD[m0 + ty + 16 * r] = acc[r][r];
    }
}

// ---------------------------------------------------------------------------
// K2: sum partials -> G, inv, ds row-sums (slots), contrastive (slots).
// 512 blocks x 256 threads: mat = b>>8, row i = b&255, thread = column j.
// ---------------------------------------------------------------------------
__global__ __launch_bounds__(256) void prep_kernel(float* __restrict__ ws) {
    __shared__ float red1[4], red2[4], redS[1];
    const int b = blockIdx.x, t = threadIdx.x;

    const int mat = b >> 8, i = b & 255, j = t;
    const float* P  = ws + OFF_PART + (unsigned)mat * 65536u;
    const float* PD = ws + OFF_PDIAG + (unsigned)mat * 256u;
    float g = 0.f, dj = 0.f, di = 0.f;
    #pragma unroll
    for (int c = 0; c < 8; ++c) {
        g  += P[c * 131072 + i * 256 + j];
        dj += PD[c * 512 + j];
        di += PD[c * 512 + i];
    }
    float* G  = ws + (mat ? OFF_GT : OFF_GS);
    float* IV = ws + (mat ? OFF_INVT : OFF_INVS);
    G[i * 256 + j] = g;
    const float d = fmaxf(di + dj - 2.f * g, 0.f);
    IV[i * 256 + j] = 1.f / (sqrtf(d) + EPSF);

    const float v = block_reduce_sum((j > i) ? d : 0.f, red1);
    if (t == 0) ws[OFF_SLOT + SL_DSDT + b] = v;

    if (b < 128) {  // contrastive row i (block-uniform branch)
        const float s = (j >= 128) ? 20.f * g : -INFINITY;
        if (j == 128 + i) redS[0] = s;          // diag score
        float m = wave_reduce_max(s);
        __syncthreads();
        if ((t & 63) == 0) red2[t >> 6] = m;
        __syncthreads();
        const float mx = fmaxf(fmaxf(red2[0], red2[1]), fmaxf(red2[2], red2[3]));
        const float e = block_reduce_sum((j >= 128) ? expf(s - mx) : 0.f, red1);
        if (t == 0) ws[OFF_SLOT + SL_CON + b] = mx + logf(e) - redS[0];
    }
}

// ---------------------------------------------------------------------------
// K3: angle (blocks 0..511) + dist (512..767). NO fences, NO atomics —
// slot writes are plain stores; K4's kernel boundary provides coherence.
// ---------------------------------------------------------------------------
__global__ __launch_bounds__(256) void angle_kernel(float* __restrict__ ws) {
    const float* Gs = ws + OFF_GS;
    const float* Gt = ws + OFF_GT;
    const float* IS = ws + OFF_INVS;
    const float* IT = ws + OFF_INVT;
    __shared__ float sGJ[16][68], sIJ[16][68], sTJ[16][68], sITJ[16][68];
    __shared__ float red1[4], red2[4];
    const int b = blockIdx.x, t = threadIdx.x;

    if (b < 512) {
        const int k0 = (b & 3) * 64;
        const int j0 = ((b >> 2) & 15) * 16;
        const int i0 = (b >> 6) * 32;
        const int jj = t & 15, ii = t >> 4;
        const int i1 = i0 + ii, i2 = i1 + 16, j = j0 + jj;
        {
            const int r = t >> 4, c = (t & 15) * 4;
            const int g = (j0 + r) * N2 + k0 + c;
            *(float4*)&sGJ[r][c]  = *(const float4*)&Gs[g];
            *(float4*)&sIJ[r][c]  = *(const float4*)&IS[g];
            *(float4*)&sTJ[r][c]  = *(const float4*)&Gt[g];
            *(float4*)&sITJ[r][c] = *(const float4*)&IT[g];
        }
        const float Gjj = Gs[j * 257], Tjj = Gt[j * 257];
        const float wis1 = IS[i1 * N2 + j], wit1 = IT[i1 * N2 + j];
        const float wis2 = IS[i2 * N2 + j], wit2 = IT[i2 * N2 + j];
        const float as1 = (Gjj - Gs[i1 * N2 + j]) * wis1;
        const float at1 = (Tjj - Gt[i1 * N2 + j]) * wit1;
        const float as2 = (Gjj - Gs[i2 * N2 + j]) * wis2;
        const float at2 = (Tjj - Gt[i2 * N2 + j]) * wit2;
        const float* gI1 = Gs + i1 * N2 + k0;
        const float* tI1 = Gt + i1 * N2 + k0;
        const float* gI2 = Gs + i2 * N2 + k0;
        const float* tI2 = Gt + i2 * N2 + k0;
        __syncthreads();

        float sum1 = 0.f, sum2 = 0.f;
        for (int c = 0; c < 64; c += 4) {
            const float4 gJ  = *(const float4*)&sGJ[jj][c];
            const float4 iJ  = *(const float4*)&sIJ[jj][c];
            const float4 tJ  = *(const float4*)&sTJ[jj][c];
            const float4 itJ = *(const float4*)&sITJ[jj][c];
            const float4 a1 = *(const float4*)&gI1[c];
            const float4 b1 = *(const float4*)&tI1[c];
            const float4 a2 = *(const float4*)&gI2[c];
            const float4 b2 = *(const float4*)&tI2[c];
            const float gJr[4]  = {gJ.x, gJ.y, gJ.z, gJ.w};
            const float iJr[4]  = {iJ.x, iJ.y, iJ.z, iJ.w};
            const float tJr[4]  = {tJ.x, tJ.y, tJ.z, tJ.w};
            const float itJr[4] = {itJ.x, itJ.y, itJ.z, itJ.w};
            const float a1r[4] = {a1.x, a1.y, a1.z, a1.w};
            const float b1r[4] = {b1.x, b1.y, b1.z, b1.w};
            const float a2r[4] = {a2.x, a2.y, a2.z, a2.w};
            const float b2r[4] = {b2.x, b2.y, b2.z, b2.w};
            #pragma unroll
            for (int e = 0; e < 4; ++e) {
                const float ps1 = fmaf(wis1, a1r[e] - gJr[e], as1) * iJr[e];
                const float pt1 = fmaf(wit1, b1r[e] - tJr[e], at1) * itJr[e];
                const float d1 = ps1 - pt1;
                const float ad1 = fabsf(d1);
                const float m1 = fminf(ad1, 1.f);
                sum1 = fmaf(m1, fmaf(-0.5f, m1, ad1), sum1);

                const float ps2 = fmaf(wis2, a2r[e] - gJr[e], as2) * iJr[e];
                const float pt2 = fmaf(wit2, b2r[e] - tJr[e], at2) * itJr[e];
                const float d2 = ps2 - pt2;
                const float ad2 = fabsf(d2);
                const float m2 = fminf(ad2, 1.f);
                sum2 = fmaf(m2, fmaf(-0.5f, m2, ad2), sum2);
            }
        }
        const float v = block_reduce_sum(sum1 + sum2, red1);
        if (t == 0) ws[OFF_SLOT + SL_ANG + b] = v;
    } else {
        // distance loss, row i = b-512
        const float sds = block_reduce_sum(ws[OFF_SLOT + SL_DSDT + t], red1);
        const float sdt = block_reduce_sum(ws[OFF_SLOT + SL_DSDT + 256 + t], red2);
        const float rs = 1.f / (sds / 32640.f + EPSF);
        const float rt = 1.f / (sdt / 32640.f + EPSF);
        const int i = b - 512;
        const float dsv = fmaxf(Gs[i * 257] + Gs[t * 257] - 2.f * Gs[i * N2 + t], 0.f);
        const float dtv = fmaxf(Gt[i * 257] + Gt[t * 257] - 2.f * Gt[i * N2 + t], 0.f);
        const float dd = dsv * rs - dtv * rt;
        const float a = fabsf(dd);
        const float m = fminf(a, 1.f);
        const float hv = block_reduce_sum((t > i) ? m * fmaf(-0.5f, m, a) : 0.f, red1);
        if (t == 0) ws[OFF_SLOT + SL_DIST + i] = hv;
    }
}

// ---------------------------------------------------------------------------
// K4: finalize. 1 block x 256 threads; kernel boundary = coherence point.
// ---------------------------------------------------------------------------
__global__ __launch_bounds__(256) void finalize_kernel(const float* __restrict__ ws,
                                                       float* __restrict__ out) {
    __shared__ float red1[4];
    const int t = threadIdx.x;
    const float* S = ws + OFF_SLOT;
    const float c_ = block_reduce_sum((t < 128) ? S[SL_CON + t] : 0.f, red1);
    const float a_ = block_reduce_sum(S[SL_ANG + t] + S[SL_ANG + 256 + t], red1);
    const float d_ = block_reduce_sum(S[SL_DIST + t], red1);
    if (t == 0) {
        const float contrastive = c_ / 128.f;
        const float dist = d_ / 32640.f;
        const float ang = a_ / 16581120.f;   // 256*255*254
        const float kd = 0.5f * (dist + ang);
        out[0] = contrastive + kd;
        out[1] = contrastive;
        out[2] = kd;
    }
}

extern "C" void kernel_launch(void* const* d_in, const int* in_sizes, int n_in,
                              void* d_out, int out_size, void* d_ws, size_t ws_size,
                              hipStream_t stream) {
    (void)in_sizes; (void)n_in; (void)out_size; (void)ws_size;
    const float* sq = (const float*)d_in[0];
    const float* sp = (const float*)d_in[1];
    const float* tq = (const float*)d_in[2];
    const float* tp = (const float*)d_in[3];
    float* ws  = (float*)d_ws;
    float* out = (float*)d_out;

    gemm_kernel<<<256, 256, 0, stream>>>(sq, sp, tq, tp, ws);
    prep_kernel<<<512, 256, 0, stream>>>(ws);
    angle_kernel<<<768, 256, 0, stream>>>(ws);
    finalize_kernel<<<1, 256, 0, stream>>>(ws, out);
}